// Round 2
// baseline (446.639 us; speedup 1.0000x reference)
//
#include <hip/hip_runtime.h>
#include <hip/hip_bf16.h>
#include <math.h>

// Problem constants
#define T_STEPS 100
#define H_DIM   50
#define Z_DIM   10
#define OUT_DIM 65   // Z + Z*(Z+1)/2 = 10 + 55
#define KP      25   // f16 pairs per gate column

typedef _Float16 half2v __attribute__((ext_vector_type(2)));

// ---- cross-lane primitives ----
__device__ __forceinline__ float bcast_lane(float v, int lane) {
    return __uint_as_float(__builtin_amdgcn_readlane(__float_as_uint(v), lane));
}
__device__ __forceinline__ unsigned readlane_u(unsigned v, int lane) {
    return (unsigned)__builtin_amdgcn_readlane((int)v, lane);
}
// DPP cross-lane fetch (VALU speed). bound_ctrl=1 -> invalid source reads 0.
template<int CTRL>
__device__ __forceinline__ float dpp_mov(float x) {
    return __uint_as_float((unsigned)__builtin_amdgcn_update_dpp(
        0, (int)__float_as_uint(x), CTRL, 0xF, 0xF, true));
}
#define DPP_ROW_SHL1 0x101   // lane i <- lane i+1
#define DPP_SHR1     0x111
#define DPP_SHR2     0x112
#define DPP_SHR4     0x114
#define DPP_SHR8     0x118
#define DPP_BCAST15  0x142
#define DPP_BCAST31  0x143

// ---- packed f16 helpers ----
__device__ __forceinline__ unsigned pack_h2(float lo, float hi) {
#if __has_builtin(__builtin_amdgcn_cvt_pkrtz)
    return __builtin_bit_cast(unsigned, __builtin_amdgcn_cvt_pkrtz(lo, hi));
#else
    half2v p; p.x = (_Float16)lo; p.y = (_Float16)hi;
    return __builtin_bit_cast(unsigned, p);
#endif
}
__device__ __forceinline__ float fdot2h(unsigned a, unsigned b, float c) {
#if __has_builtin(__builtin_amdgcn_fdot2)
    return __builtin_amdgcn_fdot2(__builtin_bit_cast(half2v, a),
                                  __builtin_bit_cast(half2v, b), c, false);
#else
    const half2v x = __builtin_bit_cast(half2v, a);
    const half2v y = __builtin_bit_cast(half2v, b);
    return fmaf((float)x.x, (float)y.x, fmaf((float)x.y, (float)y.y, c));
#endif
}

// ---- fast math ----
__device__ __forceinline__ float fast_rcp(float x) { return __builtin_amdgcn_rcpf(x); }
__device__ __forceinline__ float fast_rsq(float x) { return __builtin_amdgcn_rsqf(x); }
__device__ __forceinline__ float fast_sigmoid(float x) {
    return fast_rcp(1.0f + __expf(-x));
}
__device__ __forceinline__ float fast_tanh(float y) {
    return 1.0f - 2.0f * fast_rcp(__expf(2.0f * y) + 1.0f);
}

// Wave-local LDS fence: orders ds_write -> ds_read across lanes of ONE wave.
// lgkmcnt(0) drains the DS queue; "memory" clobber pins compiler ordering.
__device__ __forceinline__ void lds_fence_wave() {
    asm volatile("s_waitcnt lgkmcnt(0)" ::: "memory");
}

// =====================================================================
// Fully fused kernel. ONE block, 5 waves:
//   waves 0-2 : gru recurrence (one gate per wave), 1 barrier/step.
//   waves 3-4 : dense projection + nat transform, one wave per timestep
//               parity, consuming hist[s] from LDS one step behind.
// Barrier discipline: every wave executes exactly T_STEPS+1 s_barriers.
// All cross-lane work inside a dense step is intra-wave (lgkmcnt fences),
// so dense waves need no extra block barriers.
// =====================================================================
__global__ __launch_bounds__(320, 1)
void gru_fused_kernel(
    const float* __restrict__ carry_init,
    const float* __restrict__ W_hr, const float* __restrict__ b_hr,
    const float* __restrict__ s_r,  const float* __restrict__ o_r,
    const float* __restrict__ W_hz, const float* __restrict__ b_hz,
    const float* __restrict__ s_z,  const float* __restrict__ o_z,
    const float* __restrict__ W_hn, const float* __restrict__ b_hn,
    const float* __restrict__ s_n,  const float* __restrict__ o_n,
    const float* __restrict__ W_dense, const float* __restrict__ b_dense,
    float* __restrict__ out)
{
    const int tid  = threadIdx.x;
    const int wave = tid >> 6;          // 0..2 gru, 3..4 dense
    const int j    = tid & 63;

    __shared__ float gbuf[2][3][64];                    // double-buffered gate exchange
    __shared__ __align__(16) float hist[T_STEPS][64];   // h history (producer->consumer)
    __shared__ float Lp[2][56];                         // per-dense-wave scratch
    __shared__ float Li[2][56];
    __shared__ float Jsh[2][100];
    __shared__ float mrow[2][12];

    if (wave < 3) {
        // =============================================================
        // GRU waves — identical math to the previous (passing) version.
        // =============================================================
        const bool valid = (j < H_DIM);
        const int  jc    = valid ? j : 0;

        const float* Wg = (wave == 0) ? W_hr : (wave == 1) ? W_hz : W_hn;
        const float* bg = (wave == 0) ? b_hr : (wave == 1) ? b_hz : b_hn;
        const float* sg = (wave == 0) ? s_r  : (wave == 1) ? s_z  : s_n;
        const float* og = (wave == 0) ? o_r  : (wave == 1) ? o_z  : o_n;

        unsigned w[KP];
        #pragma unroll
        for (int k = 0; k < KP; ++k) {
            const int i0 = 2 * k, i1 = 2 * k + 1;
            w[k] = pack_h2(valid ? Wg[i0 * H_DIM + j] : 0.0f,
                           valid ? Wg[i1 * H_DIM + j] : 0.0f);
        }
        #pragma unroll
        for (int k = 0; k < KP; ++k) asm volatile("" : "+v"(w[k]));

        const float bj = valid ? bg[jc] : 0.0f;
        const float sc = sg[jc];
        const float of = og[jc];

        float h = valid ? carry_init[jc] : 0.0f;
        const float invH = 1.0f / (float)H_DIM;

        float    hsl = dpp_mov<DPP_ROW_SHL1>(h);
        unsigned hpk = pack_h2(h, hsl);

        #pragma unroll 1
        for (int t = 0; t < T_STEPS; ++t) {
            // ---- this wave's matvec via dot2 ----
            float a0 = bj, a1 = 0.0f;
            #pragma unroll
            for (int k = 0; k < KP; k += 2) {
                const unsigned s0 = readlane_u(hpk, 2 * k);
                a0 = fdot2h(s0, w[k], a0);
                if (k + 1 < KP) {
                    const unsigned s1 = readlane_u(hpk, 2 * (k + 1));
                    a1 = fdot2h(s1, w[k + 1], a1);
                }
            }
            const float a = a0 + a1;

            // ---- LN stats: 2 quantities, DPP tree ----
            float m = a, q = a * a;
            #define STAGE(C) m += dpp_mov<C>(m); q += dpp_mov<C>(q);
            STAGE(DPP_SHR1) STAGE(DPP_SHR2) STAGE(DPP_SHR4)
            STAGE(DPP_SHR8) STAGE(DPP_BCAST15) STAGE(DPP_BCAST31)
            #undef STAGE
            m = bcast_lane(m, 63); q = bcast_lane(q, 63);

            // ---- layernorm + this gate's activation ----
            const float mu  = m * invH;
            const float var = fmaxf(q * invH - mu * mu, 0.0f);
            const float g   = (a - mu) * fast_rsq(var + 1e-6f) * sc + of;
            const float val = (wave == 2) ? g : fast_sigmoid(g);   // n-gate: pre-tanh

            gbuf[t & 1][wave][j] = val;
            __syncthreads();   // barrier #(t+1)

            const float r  = gbuf[t & 1][0][j];
            const float z  = gbuf[t & 1][1][j];
            const float gn = gbuf[t & 1][2][j];
            const float n  = fast_tanh(r * gn);
            h = n + z * (h - n);              // (1-z)*n + z*h

            if (wave == 0) hist[t][j] = h;

            hsl = dpp_mov<DPP_ROW_SHL1>(h);
            hpk = pack_h2(h, hsl);
        }
        __syncthreads();       // barrier #(T+1): publishes hist[T-1]
    } else {
        // =============================================================
        // DENSE/NAT waves. dw = 0 handles even s, dw = 1 handles odd s.
        // All cross-lane exchange is intra-wave via LDS + lgkmcnt fence.
        // Lane map: l<55 -> tri entry l (dl[10+l]); 55<=l<64 -> mu_{l-55};
        //           lane 0 additionally computes mu_9.
        // =============================================================
        const int dw = wave - 3;
        int a = 0;
        #pragma unroll
        for (int x = 1; x < Z_DIM; ++x)
            if (j >= x * (x + 1) / 2) a = x;
        const int b   = j - a * (a + 1) / 2;
        const int col = (j < 55) ? (10 + j) : (j - 55);
        const float bdp = b_dense[col];
        const float bd9 = (j == 0) ? b_dense[9] : 0.0f;
        const bool isd = (j==0)|(j==2)|(j==5)|(j==9)|(j==14)|
                         (j==20)|(j==27)|(j==35)|(j==44)|(j==54);

        float* outSigma = out;           // [100][10][10]
        float* outMu    = out + 10000;   // [100][10]
        float* outJ     = out + 11000;   // [100][10][10]
        float* outHnat  = out + 21000;   // [100][10]

        auto dense_step = [&](int s) {
            // ---- dl = h_s @ W_dense + b (h from LDS, W L1-resident) ----
            float acc = bdp, acc9 = bd9;
            #pragma unroll
            for (int i = 0; i < H_DIM; ++i) {
                const float hi = hist[s][i];                 // LDS broadcast
                acc = fmaf(hi, W_dense[i * OUT_DIM + col], acc);
            }
            if (j == 0) {
                #pragma unroll
                for (int i = 0; i < H_DIM; ++i)
                    acc9 = fmaf(hist[s][i], W_dense[i * OUT_DIM + 9], acc9);
            }

            // ---- softplus on diagonal; publish Lp and mu ----
            if (j < 55) {
                float v = acc;
                if (isd) v = (v > 20.0f) ? v : log1pf(__expf(v));
                Lp[dw][j] = v;
            } else {
                mrow[dw][j - 55] = acc;
            }
            if (j == 0) mrow[dw][9] = acc9;
            lds_fence_wave();

            // ---- Sigma = L @ L^T ; mu writes ----
            if (j < 55) {
                float sgm = 0.0f;
                for (int k = 0; k <= b; ++k)
                    sgm = fmaf(Lp[dw][a * (a + 1) / 2 + k],
                               Lp[dw][b * (b + 1) / 2 + k], sgm);
                outSigma[s * 100 + a * 10 + b] = sgm;
                outSigma[s * 100 + b * 10 + a] = sgm;
            } else {
                outMu[s * 10 + (j - 55)] = acc;
            }
            if (j == 0) outMu[s * 10 + 9] = acc9;

            // ---- Linv by forward substitution: lane k owns column k ----
            if (j < Z_DIM) {
                const int k = j;
                float dinv[Z_DIM];
                #pragma unroll
                for (int i = 0; i < Z_DIM; ++i)
                    dinv[i] = 1.0f / Lp[dw][i * (i + 1) / 2 + i];
                float c[Z_DIM];
                #pragma unroll
                for (int i = 0; i < Z_DIM; ++i) c[i] = 0.0f;
                #pragma unroll
                for (int i = 0; i < Z_DIM; ++i) {
                    float sfs = 0.0f;
                    #pragma unroll
                    for (int m = 0; m < i; ++m)
                        sfs = fmaf(Lp[dw][i * (i + 1) / 2 + m], c[m], sfs);
                    if (i >= k) c[i] = (i == k) ? dinv[i] : -sfs * dinv[i];
                }
                #pragma unroll
                for (int i = 0; i < Z_DIM; ++i)
                    if (i >= k) Li[dw][i * (i + 1) / 2 + k] = c[i];
            }
            lds_fence_wave();

            // ---- J = Linv^T @ Linv ----
            if (j < 55) {
                float sj = 0.0f;
                for (int m = a; m < Z_DIM; ++m)
                    sj = fmaf(Li[dw][m * (m + 1) / 2 + a],
                              Li[dw][m * (m + 1) / 2 + b], sj);
                outJ[s * 100 + a * 10 + b] = sj;
                outJ[s * 100 + b * 10 + a] = sj;
                Jsh[dw][a * 10 + b] = sj;
                Jsh[dw][b * 10 + a] = sj;
            }
            lds_fence_wave();

            // ---- h_nat = J @ mu ----
            if (j < Z_DIM) {
                float sh = 0.0f;
                #pragma unroll
                for (int k2 = 0; k2 < Z_DIM; ++k2)
                    sh = fmaf(Jsh[dw][j * 10 + k2], mrow[dw][k2], sh);
                outHnat[s * 10 + j] = sh;
            }
        };

        #pragma unroll 1
        for (int t = 0; t < T_STEPS; ++t) {
            __syncthreads();               // barrier #(t+1): hist[t-1] visible
            const int s = t - 1;
            if (s >= 0 && (s & 1) == dw) dense_step(s);
        }
        __syncthreads();                   // barrier #(T+1): hist[T-1] visible
        if (dw == 1) dense_step(T_STEPS - 1);   // s = 99 is odd
    }
}

extern "C" void kernel_launch(void* const* d_in, const int* in_sizes, int n_in,
                              void* d_out, int out_size, void* d_ws, size_t ws_size,
                              hipStream_t stream) {
    const float* p[15];
    for (int i = 0; i < 15; ++i) p[i] = (const float*)d_in[i];

    gru_fused_kernel<<<dim3(1), dim3(320), 0, stream>>>(
        p[0],
        p[1], p[2], p[3], p[4],
        p[5], p[6], p[7], p[8],
        p[9], p[10], p[11], p[12],
        p[13], p[14],
        (float*)d_out);
}

// Round 3
// 180.792 us; speedup vs baseline: 2.4705x; 2.4705x over previous
//
#include <hip/hip_runtime.h>
#include <hip/hip_bf16.h>
#include <math.h>

// Problem constants
#define T_STEPS 100
#define H_DIM   50
#define Z_DIM   10
#define OUT_DIM 65   // Z + Z*(Z+1)/2 = 10 + 55
#define KP      25   // f16 pairs per gate column
#define NDW     4    // dense consumer waves

typedef _Float16 half2v __attribute__((ext_vector_type(2)));

// ---- cross-lane primitives ----
__device__ __forceinline__ float bcast_lane(float v, int lane) {
    return __uint_as_float(__builtin_amdgcn_readlane(__float_as_uint(v), lane));
}
__device__ __forceinline__ unsigned readlane_u(unsigned v, int lane) {
    return (unsigned)__builtin_amdgcn_readlane((int)v, lane);
}
// DPP cross-lane fetch (VALU speed). bound_ctrl=1 -> invalid source reads 0.
template<int CTRL>
__device__ __forceinline__ float dpp_mov(float x) {
    return __uint_as_float((unsigned)__builtin_amdgcn_update_dpp(
        0, (int)__float_as_uint(x), CTRL, 0xF, 0xF, true));
}
#define DPP_ROW_SHL1 0x101   // lane i <- lane i+1
#define DPP_SHR1     0x111
#define DPP_SHR2     0x112
#define DPP_SHR4     0x114
#define DPP_SHR8     0x118
#define DPP_BCAST15  0x142
#define DPP_BCAST31  0x143

// ---- packed f16 helpers ----
__device__ __forceinline__ unsigned pack_h2(float lo, float hi) {
#if __has_builtin(__builtin_amdgcn_cvt_pkrtz)
    return __builtin_bit_cast(unsigned, __builtin_amdgcn_cvt_pkrtz(lo, hi));
#else
    half2v p; p.x = (_Float16)lo; p.y = (_Float16)hi;
    return __builtin_bit_cast(unsigned, p);
#endif
}
__device__ __forceinline__ float fdot2h(unsigned a, unsigned b, float c) {
#if __has_builtin(__builtin_amdgcn_fdot2)
    return __builtin_amdgcn_fdot2(__builtin_bit_cast(half2v, a),
                                  __builtin_bit_cast(half2v, b), c, false);
#else
    const half2v x = __builtin_bit_cast(half2v, a);
    const half2v y = __builtin_bit_cast(half2v, b);
    return fmaf((float)x.x, (float)y.x, fmaf((float)x.y, (float)y.y, c));
#endif
}

// ---- fast math ----
__device__ __forceinline__ float fast_rcp(float x) { return __builtin_amdgcn_rcpf(x); }
__device__ __forceinline__ float fast_rsq(float x) { return __builtin_amdgcn_rsqf(x); }
__device__ __forceinline__ float fast_sigmoid(float x) {
    return fast_rcp(1.0f + __expf(-x));
}
__device__ __forceinline__ float fast_tanh(float y) {
    return 1.0f - 2.0f * fast_rcp(__expf(2.0f * y) + 1.0f);
}

// Wave-local LDS fence: orders ds_write -> ds_read across lanes of ONE wave.
__device__ __forceinline__ void lds_fence_wave() {
    asm volatile("s_waitcnt lgkmcnt(0)" ::: "memory");
}

// =====================================================================
// Fully fused kernel. ONE block, 5 waves, NO shared barriers after init:
//   wave 0    : gru recurrence (round-0 single-wave math, bit-identical),
//               writes hist[t] to LDS, release-stores progress flag.
//               Zero global ops in the loop -> no vmcnt anywhere.
//   waves 1-4 : dense+nat consumers, s mod 4 = wave-1. Acquire-poll the
//               flag (ds_read + s_sleep), then run the step fully
//               decoupled; their global-store latency is never observed
//               by the producer.
// =====================================================================
__global__ __launch_bounds__(64 * (1 + NDW), 1)
void gru_fused_kernel(
    const float* __restrict__ carry_init,
    const float* __restrict__ W_hr, const float* __restrict__ b_hr,
    const float* __restrict__ s_r,  const float* __restrict__ o_r,
    const float* __restrict__ W_hz, const float* __restrict__ b_hz,
    const float* __restrict__ s_z,  const float* __restrict__ o_z,
    const float* __restrict__ W_hn, const float* __restrict__ b_hn,
    const float* __restrict__ s_n,  const float* __restrict__ o_n,
    const float* __restrict__ W_dense, const float* __restrict__ b_dense,
    float* __restrict__ out)
{
    const int tid  = threadIdx.x;
    const int wave = tid >> 6;          // 0 gru, 1..4 dense
    const int j    = tid & 63;

    __shared__ __align__(16) float hist[T_STEPS][64];   // h history
    __shared__ int   prog;                              // steps completed
    __shared__ float Lp [NDW][56];                      // per-dense-wave scratch
    __shared__ float Li [NDW][56];
    __shared__ float Jsh[NDW][100];
    __shared__ float mrow[NDW][12];

    if (tid == 0) prog = 0;
    __syncthreads();     // the ONLY block barrier (flag-init publish)

    if (wave == 0) {
        // =============================================================
        // GRU wave — bit-identical math to the proven single-wave
        // version; only the history sink changed (LDS, not global).
        // =============================================================
        __builtin_amdgcn_s_setprio(1);   // don't let spin-waves steal issue

        const bool valid = (j < H_DIM);
        const int  jc    = valid ? j : 0;

        unsigned wr[KP], wz[KP], wn[KP];
        #pragma unroll
        for (int k = 0; k < KP; ++k) {
            const int i0 = 2 * k, i1 = 2 * k + 1;
            wr[k] = pack_h2(valid ? W_hr[i0 * H_DIM + j] : 0.0f,
                            valid ? W_hr[i1 * H_DIM + j] : 0.0f);
            wz[k] = pack_h2(valid ? W_hz[i0 * H_DIM + j] : 0.0f,
                            valid ? W_hz[i1 * H_DIM + j] : 0.0f);
            wn[k] = pack_h2(valid ? W_hn[i0 * H_DIM + j] : 0.0f,
                            valid ? W_hn[i1 * H_DIM + j] : 0.0f);
        }
        #pragma unroll
        for (int k = 0; k < KP; ++k)
            asm volatile("" : "+v"(wr[k]), "+v"(wz[k]), "+v"(wn[k]));

        const float bjr = valid ? b_hr[jc] : 0.0f;
        const float bjz = valid ? b_hz[jc] : 0.0f;
        const float bjn = valid ? b_hn[jc] : 0.0f;
        const float sr  = s_r[jc], og_r = o_r[jc];
        const float sz  = s_z[jc], og_z = o_z[jc];
        const float sn  = s_n[jc], og_n = o_n[jc];

        float h = valid ? carry_init[jc] : 0.0f;
        const float invH = 1.0f / (float)H_DIM;

        float    hsl = dpp_mov<DPP_ROW_SHL1>(h);
        unsigned hpk = pack_h2(h, hsl);

        #pragma unroll 1
        for (int t = 0; t < T_STEPS; ++t) {
            // ---- three matvecs via dot2 ----
            float ar0 = bjr, ar1 = 0.0f;
            float az0 = bjz, az1 = 0.0f;
            float an0 = bjn, an1 = 0.0f;
            #pragma unroll
            for (int k = 0; k < KP; k += 2) {
                const unsigned s0 = readlane_u(hpk, 2 * k);
                ar0 = fdot2h(s0, wr[k], ar0);
                az0 = fdot2h(s0, wz[k], az0);
                an0 = fdot2h(s0, wn[k], an0);
                if (k + 1 < KP) {
                    const unsigned s1 = readlane_u(hpk, 2 * (k + 1));
                    ar1 = fdot2h(s1, wr[k + 1], ar1);
                    az1 = fdot2h(s1, wz[k + 1], az1);
                    an1 = fdot2h(s1, wn[k + 1], an1);
                }
            }
            const float ar = ar0 + ar1;
            const float az = az0 + az1;
            const float an = an0 + an1;

            // ---- LN stats: 6 quantities, interleaved DPP tree ----
            float mr = ar, qr = ar * ar;
            float mz = az, qz = az * az;
            float mn = an, qn = an * an;
            #define STAGE(C)                                      \
                mr += dpp_mov<C>(mr); qr += dpp_mov<C>(qr);       \
                mz += dpp_mov<C>(mz); qz += dpp_mov<C>(qz);       \
                mn += dpp_mov<C>(mn); qn += dpp_mov<C>(qn);
            STAGE(DPP_SHR1) STAGE(DPP_SHR2) STAGE(DPP_SHR4)
            STAGE(DPP_SHR8) STAGE(DPP_BCAST15) STAGE(DPP_BCAST31)
            #undef STAGE
            mr = bcast_lane(mr, 63); qr = bcast_lane(qr, 63);
            mz = bcast_lane(mz, 63); qz = bcast_lane(qz, 63);
            mn = bcast_lane(mn, 63); qn = bcast_lane(qn, 63);

            // ---- layernorm + activations ----
            const float mu_r  = mr * invH;
            const float var_r = fmaxf(qr * invH - mu_r * mu_r, 0.0f);
            const float g_r   = (ar - mu_r) * fast_rsq(var_r + 1e-6f) * sr + og_r;
            const float r     = fast_sigmoid(g_r);

            const float mu_z  = mz * invH;
            const float var_z = fmaxf(qz * invH - mu_z * mu_z, 0.0f);
            const float g_z   = (az - mu_z) * fast_rsq(var_z + 1e-6f) * sz + og_z;
            const float z     = fast_sigmoid(g_z);

            const float mu_n  = mn * invH;
            const float var_n = fmaxf(qn * invH - mu_n * mu_n, 0.0f);
            const float g_n   = (an - mu_n) * fast_rsq(var_n + 1e-6f) * sn + og_n;
            const float n     = fast_tanh(r * g_n);

            h = n + z * (h - n);                 // (1-z)*n + z*h

            hist[t][j] = h;
            if (j == 0)
                __hip_atomic_store(&prog, t + 1, __ATOMIC_RELEASE,
                                   __HIP_MEMORY_SCOPE_WORKGROUP);

            hsl = dpp_mov<DPP_ROW_SHL1>(h);
            hpk = pack_h2(h, hsl);
        }
    } else {
        // =============================================================
        // DENSE/NAT waves (math identical to the round-2-verified code).
        // All cross-lane exchange is intra-wave via LDS + lgkmcnt fence.
        // Lane map: l<55 -> tri entry l (dl[10+l]); 55<=l<64 -> mu_{l-55};
        //           lane 0 additionally computes mu_9.
        // =============================================================
        const int dw = wave - 1;
        int a = 0;
        #pragma unroll
        for (int x = 1; x < Z_DIM; ++x)
            if (j >= x * (x + 1) / 2) a = x;
        const int b   = j - a * (a + 1) / 2;
        const int col = (j < 55) ? (10 + j) : (j - 55);
        const float bdp = b_dense[col];
        const float bd9 = (j == 0) ? b_dense[9] : 0.0f;
        const bool isd = (j==0)|(j==2)|(j==5)|(j==9)|(j==14)|
                         (j==20)|(j==27)|(j==35)|(j==44)|(j==54);

        float* outSigma = out;           // [100][10][10]
        float* outMu    = out + 10000;   // [100][10]
        float* outJ     = out + 11000;   // [100][10][10]
        float* outHnat  = out + 21000;   // [100][10]

        auto dense_step = [&](int s) {
            // ---- dl = h_s @ W_dense + b (h from LDS, W L1-resident) ----
            float acc = bdp, acc9 = bd9;
            #pragma unroll
            for (int i = 0; i < H_DIM; ++i) {
                const float hi = hist[s][i];                 // LDS broadcast
                acc = fmaf(hi, W_dense[i * OUT_DIM + col], acc);
            }
            if (j == 0) {
                #pragma unroll
                for (int i = 0; i < H_DIM; ++i)
                    acc9 = fmaf(hist[s][i], W_dense[i * OUT_DIM + 9], acc9);
            }

            // ---- softplus on diagonal; publish Lp and mu ----
            if (j < 55) {
                float v = acc;
                if (isd) v = (v > 20.0f) ? v : log1pf(__expf(v));
                Lp[dw][j] = v;
            } else {
                mrow[dw][j - 55] = acc;
            }
            if (j == 0) mrow[dw][9] = acc9;
            lds_fence_wave();

            // ---- Sigma = L @ L^T ; mu writes ----
            if (j < 55) {
                float sgm = 0.0f;
                for (int k = 0; k <= b; ++k)
                    sgm = fmaf(Lp[dw][a * (a + 1) / 2 + k],
                               Lp[dw][b * (b + 1) / 2 + k], sgm);
                outSigma[s * 100 + a * 10 + b] = sgm;
                outSigma[s * 100 + b * 10 + a] = sgm;
            } else {
                outMu[s * 10 + (j - 55)] = acc;
            }
            if (j == 0) outMu[s * 10 + 9] = acc9;

            // ---- Linv by forward substitution: lane k owns column k ----
            if (j < Z_DIM) {
                const int k = j;
                float dinv[Z_DIM];
                #pragma unroll
                for (int i = 0; i < Z_DIM; ++i)
                    dinv[i] = 1.0f / Lp[dw][i * (i + 1) / 2 + i];
                float c[Z_DIM];
                #pragma unroll
                for (int i = 0; i < Z_DIM; ++i) c[i] = 0.0f;
                #pragma unroll
                for (int i = 0; i < Z_DIM; ++i) {
                    float sfs = 0.0f;
                    #pragma unroll
                    for (int m = 0; m < i; ++m)
                        sfs = fmaf(Lp[dw][i * (i + 1) / 2 + m], c[m], sfs);
                    if (i >= k) c[i] = (i == k) ? dinv[i] : -sfs * dinv[i];
                }
                #pragma unroll
                for (int i = 0; i < Z_DIM; ++i)
                    if (i >= k) Li[dw][i * (i + 1) / 2 + k] = c[i];
            }
            lds_fence_wave();

            // ---- J = Linv^T @ Linv ----
            if (j < 55) {
                float sj = 0.0f;
                for (int m = a; m < Z_DIM; ++m)
                    sj = fmaf(Li[dw][m * (m + 1) / 2 + a],
                              Li[dw][m * (m + 1) / 2 + b], sj);
                outJ[s * 100 + a * 10 + b] = sj;
                outJ[s * 100 + b * 10 + a] = sj;
                Jsh[dw][a * 10 + b] = sj;
                Jsh[dw][b * 10 + a] = sj;
            }
            lds_fence_wave();

            // ---- h_nat = J @ mu ----
            if (j < Z_DIM) {
                float sh = 0.0f;
                #pragma unroll
                for (int k2 = 0; k2 < Z_DIM; ++k2)
                    sh = fmaf(Jsh[dw][j * 10 + k2], mrow[dw][k2], sh);
                outHnat[s * 10 + j] = sh;
            }
        };

        #pragma unroll 1
        for (int s = dw; s < T_STEPS; s += NDW) {
            // acquire-poll: wait until producer has published hist[s]
            while (__hip_atomic_load(&prog, __ATOMIC_ACQUIRE,
                                     __HIP_MEMORY_SCOPE_WORKGROUP) <= s)
                __builtin_amdgcn_s_sleep(1);
            dense_step(s);
        }
    }
}

extern "C" void kernel_launch(void* const* d_in, const int* in_sizes, int n_in,
                              void* d_out, int out_size, void* d_ws, size_t ws_size,
                              hipStream_t stream) {
    const float* p[15];
    for (int i = 0; i < 15; ++i) p[i] = (const float*)d_in[i];

    gru_fused_kernel<<<dim3(1), dim3(64 * (1 + NDW)), 0, stream>>>(
        p[0],
        p[1], p[2], p[3], p[4],
        p[5], p[6], p[7], p[8],
        p[9], p[10], p[11], p[12],
        p[13], p[14],
        (float*)d_out);
}

// Round 4
// 128.383 us; speedup vs baseline: 3.4790x; 1.4082x over previous
//
#include <hip/hip_runtime.h>
#include <hip/hip_bf16.h>
#include <math.h>

// Problem constants
#define T_STEPS 100
#define H_DIM   50
#define Z_DIM   10
#define OUT_DIM 65   // Z + Z*(Z+1)/2 = 10 + 55
#define KP      25   // f16 pairs per gate column

typedef _Float16 half2v __attribute__((ext_vector_type(2)));

// ---- cross-lane primitives ----
__device__ __forceinline__ float bcast_lane(float v, int lane) {
    return __uint_as_float(__builtin_amdgcn_readlane(__float_as_uint(v), lane));
}
__device__ __forceinline__ unsigned readlane_u(unsigned v, int lane) {
    return (unsigned)__builtin_amdgcn_readlane((int)v, lane);
}
// DPP cross-lane fetch (VALU speed). bound_ctrl=1 -> invalid source reads 0.
template<int CTRL>
__device__ __forceinline__ float dpp_mov(float x) {
    return __uint_as_float((unsigned)__builtin_amdgcn_update_dpp(
        0, (int)__float_as_uint(x), CTRL, 0xF, 0xF, true));
}
#define DPP_ROW_SHL1 0x101   // lane i <- lane i+1
#define DPP_SHR1     0x111
#define DPP_SHR2     0x112
#define DPP_SHR4     0x114
#define DPP_SHR8     0x118
#define DPP_BCAST15  0x142
#define DPP_BCAST31  0x143

// ---- packed f16 helpers ----
__device__ __forceinline__ unsigned pack_h2(float lo, float hi) {
#if __has_builtin(__builtin_amdgcn_cvt_pkrtz)
    return __builtin_bit_cast(unsigned, __builtin_amdgcn_cvt_pkrtz(lo, hi));
#else
    half2v p; p.x = (_Float16)lo; p.y = (_Float16)hi;
    return __builtin_bit_cast(unsigned, p);
#endif
}
__device__ __forceinline__ float fdot2h(unsigned a, unsigned b, float c) {
#if __has_builtin(__builtin_amdgcn_fdot2)
    return __builtin_amdgcn_fdot2(__builtin_bit_cast(half2v, a),
                                  __builtin_bit_cast(half2v, b), c, false);
#else
    const half2v x = __builtin_bit_cast(half2v, a);
    const half2v y = __builtin_bit_cast(half2v, b);
    return fmaf((float)x.x, (float)y.x, fmaf((float)x.y, (float)y.y, c));
#endif
}

// ---- fast math ----
__device__ __forceinline__ float fast_rcp(float x) { return __builtin_amdgcn_rcpf(x); }
__device__ __forceinline__ float fast_rsq(float x) { return __builtin_amdgcn_rsqf(x); }
__device__ __forceinline__ float fast_sigmoid(float x) {
    return fast_rcp(1.0f + __expf(-x));
}
__device__ __forceinline__ float fast_tanh(float y) {
    return 1.0f - 2.0f * fast_rcp(__expf(2.0f * y) + 1.0f);
}

// =====================================================================
// Kernel 1: serial recurrence, 3 waves (one gate per wave).
// Restored round-1 structure (proven 53 µs) with two chain-latency
// edits: 4-chain matvec (dep depth 13 -> 7) and single-ds_read_b128
// gate exchange (gbuf stored as float4 per j).
// =====================================================================
__global__ __launch_bounds__(192, 1)
void gru_recur_kernel(
    const float* __restrict__ carry_init,
    const float* __restrict__ W_hr, const float* __restrict__ b_hr,
    const float* __restrict__ s_r,  const float* __restrict__ o_r,
    const float* __restrict__ W_hz, const float* __restrict__ b_hz,
    const float* __restrict__ s_z,  const float* __restrict__ o_z,
    const float* __restrict__ W_hn, const float* __restrict__ b_hn,
    const float* __restrict__ s_n,  const float* __restrict__ o_n,
    float* __restrict__ ws_h)
{
    const int  tid   = threadIdx.x;
    const int  wave  = tid >> 6;          // 0:r  1:z  2:n
    const int  j     = tid & 63;
    const bool valid = (j < H_DIM);
    const int  jc    = valid ? j : 0;

    // Per-wave gate parameter selection (wave-uniform branches).
    const float* Wg = (wave == 0) ? W_hr : (wave == 1) ? W_hz : W_hn;
    const float* bg = (wave == 0) ? b_hr : (wave == 1) ? b_hz : b_hn;
    const float* sg = (wave == 0) ? s_r  : (wave == 1) ? s_z  : s_n;
    const float* og = (wave == 0) ? o_r  : (wave == 1) ? o_z  : o_n;

    // Lane j: column j of this wave's gate W, packed f16 pairs over K.
    unsigned w[KP];
    #pragma unroll
    for (int k = 0; k < KP; ++k) {
        const int i0 = 2 * k, i1 = 2 * k + 1;
        w[k] = pack_h2(valid ? Wg[i0 * H_DIM + j] : 0.0f,
                       valid ? Wg[i1 * H_DIM + j] : 0.0f);
    }
    #pragma unroll
    for (int k = 0; k < KP; ++k) asm volatile("" : "+v"(w[k]));

    const float bj = valid ? bg[jc] : 0.0f;
    const float sc = sg[jc];
    const float of = og[jc];

    __shared__ __align__(16) float4 gbuf[2][64];        // x:r y:z z:g_n (double-buffered)
    __shared__ __align__(16) float  hist[T_STEPS][64];  // h history, dumped at end

    float h = valid ? carry_init[jc] : 0.0f;
    const float invH = 1.0f / (float)H_DIM;

    // Packed broadcast source: even lane 2k holds (h_2k, h_{2k+1}).
    float    hsl = dpp_mov<DPP_ROW_SHL1>(h);
    unsigned hpk = pack_h2(h, hsl);

    #pragma unroll 1
    for (int t = 0; t < T_STEPS; ++t) {
        // ---- this wave's matvec via dot2, 4 chains (depth 7) ----
        float a0 = bj, a1 = 0.0f, a2 = 0.0f, a3 = 0.0f;
        #pragma unroll
        for (int k = 0; k < KP; k += 4) {
            const unsigned s0 = readlane_u(hpk, 2 * k);
            a0 = fdot2h(s0, w[k], a0);
            if (k + 1 < KP) {
                const unsigned s1 = readlane_u(hpk, 2 * (k + 1));
                a1 = fdot2h(s1, w[k + 1], a1);
            }
            if (k + 2 < KP) {
                const unsigned s2 = readlane_u(hpk, 2 * (k + 2));
                a2 = fdot2h(s2, w[k + 2], a2);
            }
            if (k + 3 < KP) {
                const unsigned s3 = readlane_u(hpk, 2 * (k + 3));
                a3 = fdot2h(s3, w[k + 3], a3);
            }
        }
        const float a = (a0 + a1) + (a2 + a3);

        // ---- LN stats: 2 quantities, DPP tree ----
        float m = a, q = a * a;
        #define STAGE(C) m += dpp_mov<C>(m); q += dpp_mov<C>(q);
        STAGE(DPP_SHR1) STAGE(DPP_SHR2) STAGE(DPP_SHR4)
        STAGE(DPP_SHR8) STAGE(DPP_BCAST15) STAGE(DPP_BCAST31)
        #undef STAGE
        m = bcast_lane(m, 63); q = bcast_lane(q, 63);

        // ---- layernorm + this gate's activation ----
        const float mu  = m * invH;
        const float var = fmaxf(q * invH - mu * mu, 0.0f);
        const float g   = (a - mu) * fast_rsq(var + 1e-6f) * sc + of;
        const float val = (wave == 2) ? g : fast_sigmoid(g);   // n-gate: pre-tanh

        ((float*)&gbuf[t & 1][j])[wave] = val;
        __syncthreads();   // one barrier/step; double buffer makes it sufficient

        // ---- combine (redundant in all 3 waves), one b128 read ----
        const float4 gv = gbuf[t & 1][j];
        const float  n  = fast_tanh(gv.x * gv.z);
        h = n + gv.y * (h - n);           // (1-z)*n + z*h

        if (wave == 0) hist[t][j] = h;

        // repack broadcast source for next step
        hsl = dpp_mov<DPP_ROW_SHL1>(h);
        hpk = pack_h2(h, hsl);
    }

    __syncthreads();
    // Vectorized LDS -> global dump of the whole history.
    {
        float4*       dst = (float4*)ws_h;
        const float4* src = (const float4*)hist;
        for (int i = tid; i < T_STEPS * 16; i += 192)
            dst[i] = src[i];
    }
}

// =====================================================================
// Kernel 2: dense projection + nat transform. One block per timestep,
// parallel across CUs. (Verbatim round-1 version.)
// =====================================================================
__global__ __launch_bounds__(128)
void dense_nat_kernel(
    const float* __restrict__ W_dense, const float* __restrict__ b_dense,
    const float* __restrict__ ws_h, float* __restrict__ out)
{
    const int t   = blockIdx.x;
    const int tid = threadIdx.x;

    __shared__ float hloc[H_DIM];
    __shared__ float dl  [OUT_DIM];
    __shared__ float Lp  [55];
    __shared__ float Li  [55];
    __shared__ float Jsh [100];

    if (tid < H_DIM) hloc[tid] = ws_h[t * 64 + tid];
    __syncthreads();

    if (tid < OUT_DIM) {
        float acc = b_dense[tid];
        #pragma unroll
        for (int i = 0; i < H_DIM; ++i)
            acc = fmaf(hloc[i], W_dense[i * OUT_DIM + tid], acc);
        dl[tid] = acc;
    }
    __syncthreads();

    // Lp = packed lower-tri L with softplus applied to diagonal entries.
    if (tid < 55) {
        float v = dl[Z_DIM + tid];
        const bool isd = (tid==0)|(tid==2)|(tid==5)|(tid==9)|(tid==14)|
                         (tid==20)|(tid==27)|(tid==35)|(tid==44)|(tid==54);
        if (isd) v = (v > 20.0f) ? v : log1pf(__expf(v));
        Lp[tid] = v;
    }
    __syncthreads();

    float* outSigma = out;           // [100][10][10]
    float* outMu    = out + 10000;   // [100][10]
    float* outJ     = out + 11000;   // [100][10][10]
    float* outHnat  = out + 21000;   // [100][10]

    // Map flat tri index -> (a,b), a >= b
    int a = 0;
    {
        #pragma unroll
        for (int x = 1; x < Z_DIM; ++x)
            if (tid >= x * (x + 1) / 2) a = x;
    }
    const int b = tid - a * (a + 1) / 2;

    // Sigma = L @ L^T (one entry per thread)
    if (tid < 55) {
        float s = 0.0f;
        for (int k = 0; k <= b; ++k)
            s = fmaf(Lp[a * (a + 1) / 2 + k], Lp[b * (b + 1) / 2 + k], s);
        outSigma[t * 100 + a * 10 + b] = s;
        outSigma[t * 100 + b * 10 + a] = s;
    }
    if (tid >= 64 && tid < 64 + Z_DIM) outMu[t * 10 + (tid - 64)] = dl[tid - 64];
    __syncthreads();

    // Linv by forward substitution: thread k owns column k in registers.
    if (tid < Z_DIM) {
        const int k = tid;
        float dinv[Z_DIM];
        #pragma unroll
        for (int i = 0; i < Z_DIM; ++i)
            dinv[i] = 1.0f / Lp[i * (i + 1) / 2 + i];
        float col[Z_DIM];
        #pragma unroll
        for (int i = 0; i < Z_DIM; ++i) col[i] = 0.0f;
        #pragma unroll
        for (int i = 0; i < Z_DIM; ++i) {
            float s = 0.0f;
            #pragma unroll
            for (int m = 0; m < i; ++m)
                s = fmaf(Lp[i * (i + 1) / 2 + m], col[m], s);
            if (i >= k) col[i] = (i == k) ? dinv[i] : -s * dinv[i];
        }
        #pragma unroll
        for (int i = 0; i < Z_DIM; ++i)
            if (i >= k) Li[i * (i + 1) / 2 + k] = col[i];
    }
    __syncthreads();

    // J = Linv^T @ Linv (one entry per thread)
    if (tid < 55) {
        float s = 0.0f;
        for (int m = a; m < Z_DIM; ++m)
            s = fmaf(Li[m * (m + 1) / 2 + a], Li[m * (m + 1) / 2 + b], s);
        outJ[t * 100 + a * 10 + b] = s;
        outJ[t * 100 + b * 10 + a] = s;
        Jsh[a * 10 + b] = s;
        Jsh[b * 10 + a] = s;
    }
    __syncthreads();

    // h_nat = J @ mu
    if (tid < Z_DIM) {
        float s = 0.0f;
        #pragma unroll
        for (int k = 0; k < Z_DIM; ++k)
            s = fmaf(Jsh[tid * 10 + k], dl[k], s);
        outHnat[t * 10 + tid] = s;
    }
}

extern "C" void kernel_launch(void* const* d_in, const int* in_sizes, int n_in,
                              void* d_out, int out_size, void* d_ws, size_t ws_size,
                              hipStream_t stream) {
    const float* p[15];
    for (int i = 0; i < 15; ++i) p[i] = (const float*)d_in[i];
    float* ws_h = (float*)d_ws;   // [T_STEPS][64] f32 = 25600 B

    gru_recur_kernel<<<dim3(1), dim3(192), 0, stream>>>(
        p[0],
        p[1], p[2], p[3], p[4],
        p[5], p[6], p[7], p[8],
        p[9], p[10], p[11], p[12],
        ws_h);

    dense_nat_kernel<<<dim3(T_STEPS), dim3(128), 0, stream>>>(
        p[13], p[14], ws_h, (float*)d_out);
}

// Round 5
// 124.171 us; speedup vs baseline: 3.5970x; 1.0339x over previous
//
#include <hip/hip_runtime.h>
#include <hip/hip_bf16.h>
#include <math.h>

// Problem constants
#define T_STEPS 100
#define H_DIM   50
#define Z_DIM   10
#define OUT_DIM 65   // Z + Z*(Z+1)/2 = 10 + 55
#define KP      25   // f16 pairs per gate column

typedef _Float16 half2v __attribute__((ext_vector_type(2)));

// ---- cross-lane primitives ----
__device__ __forceinline__ float bcast_lane(float v, int lane) {
    return __uint_as_float(__builtin_amdgcn_readlane(__float_as_uint(v), lane));
}
__device__ __forceinline__ unsigned readlane_u(unsigned v, int lane) {
    return (unsigned)__builtin_amdgcn_readlane((int)v, lane);
}
// DPP cross-lane fetch (VALU speed). bound_ctrl=1 -> invalid source reads 0.
template<int CTRL>
__device__ __forceinline__ float dpp_mov(float x) {
    return __uint_as_float((unsigned)__builtin_amdgcn_update_dpp(
        0, (int)__float_as_uint(x), CTRL, 0xF, 0xF, true));
}
#define DPP_ROW_SHL1 0x101   // lane i <- lane i+1
#define DPP_SHR1     0x111
#define DPP_SHR2     0x112
#define DPP_SHR4     0x114
#define DPP_SHR8     0x118
#define DPP_BCAST15  0x142
#define DPP_BCAST31  0x143

// ---- packed f16 helpers ----
__device__ __forceinline__ unsigned pack_h2(float lo, float hi) {
#if __has_builtin(__builtin_amdgcn_cvt_pkrtz)
    return __builtin_bit_cast(unsigned, __builtin_amdgcn_cvt_pkrtz(lo, hi));
#else
    half2v p; p.x = (_Float16)lo; p.y = (_Float16)hi;
    return __builtin_bit_cast(unsigned, p);
#endif
}
__device__ __forceinline__ float fdot2h(unsigned a, unsigned b, float c) {
#if __has_builtin(__builtin_amdgcn_fdot2)
    return __builtin_amdgcn_fdot2(__builtin_bit_cast(half2v, a),
                                  __builtin_bit_cast(half2v, b), c, false);
#else
    const half2v x = __builtin_bit_cast(half2v, a);
    const half2v y = __builtin_bit_cast(half2v, b);
    return fmaf((float)x.x, (float)y.x, fmaf((float)x.y, (float)y.y, c));
#endif
}

// ---- fast math ----
__device__ __forceinline__ float fast_rcp(float x) { return __builtin_amdgcn_rcpf(x); }
__device__ __forceinline__ float fast_rsq(float x) { return __builtin_amdgcn_rsqf(x); }
__device__ __forceinline__ float fast_sigmoid(float x) {
    return fast_rcp(1.0f + __expf(-x));
}
__device__ __forceinline__ float fast_tanh(float y) {
    return 1.0f - 2.0f * fast_rcp(__expf(2.0f * y) + 1.0f);
}

// =====================================================================
// Kernel 1: serial recurrence, 3 waves (one gate per wave).
// Exact round-1 structure (best measured: 53.0 us) with ONE change:
// all 25 v_readlane broadcasts are hoisted into an SGPR array BEFORE
// the dot2 chains and pinned there, so the VALU-writes-SGPR ->
// VALU-reads-SGPR wait-state hazard (readlane immediately before its
// consuming v_dot2) is fully pipelined away instead of paid 25x/step.
// =====================================================================
__global__ __launch_bounds__(192, 1)
void gru_recur_kernel(
    const float* __restrict__ carry_init,
    const float* __restrict__ W_hr, const float* __restrict__ b_hr,
    const float* __restrict__ s_r,  const float* __restrict__ o_r,
    const float* __restrict__ W_hz, const float* __restrict__ b_hz,
    const float* __restrict__ s_z,  const float* __restrict__ o_z,
    const float* __restrict__ W_hn, const float* __restrict__ b_hn,
    const float* __restrict__ s_n,  const float* __restrict__ o_n,
    float* __restrict__ ws_h)
{
    const int  tid   = threadIdx.x;
    const int  wave  = tid >> 6;          // 0:r  1:z  2:n
    const int  j     = tid & 63;
    const bool valid = (j < H_DIM);
    const int  jc    = valid ? j : 0;

    // Per-wave gate parameter selection (wave-uniform branches).
    const float* Wg = (wave == 0) ? W_hr : (wave == 1) ? W_hz : W_hn;
    const float* bg = (wave == 0) ? b_hr : (wave == 1) ? b_hz : b_hn;
    const float* sg = (wave == 0) ? s_r  : (wave == 1) ? s_z  : s_n;
    const float* og = (wave == 0) ? o_r  : (wave == 1) ? o_z  : o_n;

    // Lane j: column j of this wave's gate W, packed f16 pairs over K.
    // Invalid lanes get zero weights/bias -> activations exactly 0 ->
    // LN stats need no masking.
    unsigned w[KP];
    #pragma unroll
    for (int k = 0; k < KP; ++k) {
        const int i0 = 2 * k, i1 = 2 * k + 1;
        w[k] = pack_h2(valid ? Wg[i0 * H_DIM + j] : 0.0f,
                       valid ? Wg[i1 * H_DIM + j] : 0.0f);
    }
    // Pin: forbid rematerializing the loads/converts inside the t-loop.
    #pragma unroll
    for (int k = 0; k < KP; ++k) asm volatile("" : "+v"(w[k]));

    const float bj = valid ? bg[jc] : 0.0f;
    const float sc = sg[jc];
    const float of = og[jc];

    __shared__ float gbuf[2][3][64];                    // double-buffered gate exchange
    __shared__ __align__(16) float hist[T_STEPS][64];   // h history, dumped at end

    float h = valid ? carry_init[jc] : 0.0f;
    const float invH = 1.0f / (float)H_DIM;

    // Packed broadcast source: even lane 2k holds (h_2k, h_{2k+1}).
    // row_shl:1 (lane i <- i+1) stays in-row since 2k is even.
    float    hsl = dpp_mov<DPP_ROW_SHL1>(h);
    unsigned hpk = pack_h2(h, hsl);

    #pragma unroll 1
    for (int t = 0; t < T_STEPS; ++t) {
        // ---- hoisted broadcasts: 25 independent readlanes -> SGPRs ----
        // Issued back-to-back so they pipeline; by the time the first
        // dot2 consumes hs[0], its SGPR write is long retired.
        unsigned hs[KP];
        #pragma unroll
        for (int k = 0; k < KP; ++k) hs[k] = readlane_u(hpk, 2 * k);
        #pragma unroll
        for (int k = 0; k < KP; ++k) asm volatile("" : "+s"(hs[k]));

        // ---- this wave's matvec via dot2: a_j = b_j + sum_i h_i*W[i][j] ----
        float a0 = bj, a1 = 0.0f;
        #pragma unroll
        for (int k = 0; k < KP; k += 2) {
            a0 = fdot2h(hs[k], w[k], a0);
            if (k + 1 < KP) a1 = fdot2h(hs[k + 1], w[k + 1], a1);
        }
        const float a = a0 + a1;

        // ---- LN stats: 2 quantities, DPP tree ----
        float m = a, q = a * a;
        #define STAGE(C) m += dpp_mov<C>(m); q += dpp_mov<C>(q);
        STAGE(DPP_SHR1) STAGE(DPP_SHR2) STAGE(DPP_SHR4)
        STAGE(DPP_SHR8) STAGE(DPP_BCAST15) STAGE(DPP_BCAST31)
        #undef STAGE
        m = bcast_lane(m, 63); q = bcast_lane(q, 63);

        // ---- layernorm + this gate's activation ----
        const float mu  = m * invH;
        const float var = fmaxf(q * invH - mu * mu, 0.0f);
        const float g   = (a - mu) * fast_rsq(var + 1e-6f) * sc + of;
        const float val = (wave == 2) ? g : fast_sigmoid(g);   // n-gate: pre-tanh

        gbuf[t & 1][wave][j] = val;
        __syncthreads();   // one barrier/step; double buffer makes it sufficient

        // ---- combine (redundant in all 3 waves) ----
        const float r  = gbuf[t & 1][0][j];
        const float z  = gbuf[t & 1][1][j];
        const float gn = gbuf[t & 1][2][j];
        const float n  = fast_tanh(r * gn);
        h = n + z * (h - n);              // (1-z)*n + z*h

        if (wave == 0) hist[t][j] = h;

        // repack broadcast source for next step
        hsl = dpp_mov<DPP_ROW_SHL1>(h);
        hpk = pack_h2(h, hsl);
    }

    __syncthreads();
    // Vectorized LDS -> global dump of the whole history.
    {
        float4*       dst = (float4*)ws_h;
        const float4* src = (const float4*)hist;
        for (int i = tid; i < T_STEPS * 16; i += 192)
            dst[i] = src[i];
    }
}

// =====================================================================
// Kernel 2: dense projection + nat transform. One block per timestep,
// parallel across CUs. (Verbatim round-1 version.)
// =====================================================================
__global__ __launch_bounds__(128)
void dense_nat_kernel(
    const float* __restrict__ W_dense, const float* __restrict__ b_dense,
    const float* __restrict__ ws_h, float* __restrict__ out)
{
    const int t   = blockIdx.x;
    const int tid = threadIdx.x;

    __shared__ float hloc[H_DIM];
    __shared__ float dl  [OUT_DIM];
    __shared__ float Lp  [55];
    __shared__ float Li  [55];
    __shared__ float Jsh [100];

    if (tid < H_DIM) hloc[tid] = ws_h[t * 64 + tid];
    __syncthreads();

    if (tid < OUT_DIM) {
        float acc = b_dense[tid];
        #pragma unroll
        for (int i = 0; i < H_DIM; ++i)
            acc = fmaf(hloc[i], W_dense[i * OUT_DIM + tid], acc);
        dl[tid] = acc;
    }
    __syncthreads();

    // Lp = packed lower-tri L with softplus applied to diagonal entries.
    if (tid < 55) {
        float v = dl[Z_DIM + tid];
        const bool isd = (tid==0)|(tid==2)|(tid==5)|(tid==9)|(tid==14)|
                         (tid==20)|(tid==27)|(tid==35)|(tid==44)|(tid==54);
        if (isd) v = (v > 20.0f) ? v : log1pf(__expf(v));
        Lp[tid] = v;
    }
    __syncthreads();

    float* outSigma = out;           // [100][10][10]
    float* outMu    = out + 10000;   // [100][10]
    float* outJ     = out + 11000;   // [100][10][10]
    float* outHnat  = out + 21000;   // [100][10]

    // Map flat tri index -> (a,b), a >= b
    int a = 0;
    {
        #pragma unroll
        for (int x = 1; x < Z_DIM; ++x)
            if (tid >= x * (x + 1) / 2) a = x;
    }
    const int b = tid - a * (a + 1) / 2;

    // Sigma = L @ L^T (one entry per thread)
    if (tid < 55) {
        float s = 0.0f;
        for (int k = 0; k <= b; ++k)
            s = fmaf(Lp[a * (a + 1) / 2 + k], Lp[b * (b + 1) / 2 + k], s);
        outSigma[t * 100 + a * 10 + b] = s;
        outSigma[t * 100 + b * 10 + a] = s;
    }
    if (tid >= 64 && tid < 64 + Z_DIM) outMu[t * 10 + (tid - 64)] = dl[tid - 64];
    __syncthreads();

    // Linv by forward substitution: thread k owns column k in registers.
    if (tid < Z_DIM) {
        const int k = tid;
        float dinv[Z_DIM];
        #pragma unroll
        for (int i = 0; i < Z_DIM; ++i)
            dinv[i] = 1.0f / Lp[i * (i + 1) / 2 + i];
        float col[Z_DIM];
        #pragma unroll
        for (int i = 0; i < Z_DIM; ++i) col[i] = 0.0f;
        #pragma unroll
        for (int i = 0; i < Z_DIM; ++i) {
            float s = 0.0f;
            #pragma unroll
            for (int m = 0; m < i; ++m)
                s = fmaf(Lp[i * (i + 1) / 2 + m], col[m], s);
            if (i >= k) col[i] = (i == k) ? dinv[i] : -s * dinv[i];
        }
        #pragma unroll
        for (int i = 0; i < Z_DIM; ++i)
            if (i >= k) Li[i * (i + 1) / 2 + k] = col[i];
    }
    __syncthreads();

    // J = Linv^T @ Linv (one entry per thread)
    if (tid < 55) {
        float s = 0.0f;
        for (int m = a; m < Z_DIM; ++m)
            s = fmaf(Li[m * (m + 1) / 2 + a], Li[m * (m + 1) / 2 + b], s);
        outJ[t * 100 + a * 10 + b] = s;
        outJ[t * 100 + b * 10 + a] = s;
        Jsh[a * 10 + b] = s;
        Jsh[b * 10 + a] = s;
    }
    __syncthreads();

    // h_nat = J @ mu
    if (tid < Z_DIM) {
        float s = 0.0f;
        #pragma unroll
        for (int k = 0; k < Z_DIM; ++k)
            s = fmaf(Jsh[tid * 10 + k], dl[k], s);
        outHnat[t * 10 + tid] = s;
    }
}

extern "C" void kernel_launch(void* const* d_in, const int* in_sizes, int n_in,
                              void* d_out, int out_size, void* d_ws, size_t ws_size,
                              hipStream_t stream) {
    const float* p[15];
    for (int i = 0; i < 15; ++i) p[i] = (const float*)d_in[i];
    float* ws_h = (float*)d_ws;   // [T_STEPS][64] f32 = 25600 B

    gru_recur_kernel<<<dim3(1), dim3(192), 0, stream>>>(
        p[0],
        p[1], p[2], p[3], p[4],
        p[5], p[6], p[7], p[8],
        p[9], p[10], p[11], p[12],
        ws_h);

    dense_nat_kernel<<<dim3(T_STEPS), dim3(128), 0, stream>>>(
        p[13], p[14], ws_h, (float*)d_out);
}